// Round 5
// baseline (101.596 us; speedup 1.0000x reference)
//
#include <hip/hip_runtime.h>
#include <math.h>

#define E_NUM 2048
#define A_N   8
#define ROWS  (E_NUM*A_N)   // 16384

typedef __attribute__((ext_vector_type(8))) short bf16x8;
typedef __attribute__((ext_vector_type(4))) float f32x4;

__device__ __forceinline__ unsigned short f2bf(float x) {
  unsigned int u = __float_as_uint(x);
  return (unsigned short)((u + 0x7FFFu + ((u >> 16) & 1u)) >> 16);
}
#define MFMA16(a,b,c) __builtin_amdgcn_mfma_f32_16x16x32_bf16(a,b,c,0,0,0)

// ---- ws layout (float offsets) ----
#define T_WK   0         // 16*64 f32 transposed
#define T_WV1  1024      // 80*64
#define T_WV2  6144      // 64*16
#define TMB    7168      // 8*256 f32: tm_b1[o] + tm_w1[o][64+j]
#define B_WM1  9216      // 256x256 bf16 frag-major (32768 fl)
#define B_WM2  41984     // 128x256 (16384 fl)
#define B_WQ   58368     // 64x256 (8192 fl)
#define B_TM1  66560     // 256x64 (8192 fl)
#define B_TM2  74752     // 16x256 (2048 fl)
#define B_FC1  76800     // 64x160 (5120 fl)
#define B_WIH  81920     // 192x64 (6144 fl)
#define B_WHH  88064     // 192x64 (6144 fl)
#define O_ACT  94208     // 16384*16 f32
#define O_QRY  356352    // 16384*64 f32
#define O_L1P  1404928   // 256
#define O_L2P  1405184   // 256

// d_out: q_reflect [0,262144) ; h ; loss1 ; loss2
#define DO_H   262144
#define DO_L1  1310720
#define DO_L2  1310721

#define LD4(p) (*(const float4*)(p))

struct PrepP {
  const float* tsrc[3]; int tO[3], tK[3], tOff[3];
  const float* ssrc[8]; int sO[8], sK[8], sKs[8], sSt[8], sOff[8]; // sOff in ushort units
  const float* tm_w1; const float* tm_b1;
};

// blocks 0..23: f32 transpose ; 24..151: bf16 frag swizzle (w/ K zero-pad) ; 152..159: tmB
__global__ __launch_bounds__(256) void k_prep(PrepP p, float* __restrict__ ws,
                                              unsigned short* __restrict__ wsu) {
  int bid = blockIdx.x;
  if (bid < 24) {
    int b = bid >> 3, sl = bid & 7;
    const float* s = p.tsrc[b];
    float* d = ws + p.tOff[b];
    int O = p.tO[b], K = p.tK[b], n = O * K;
    for (int i = sl * 256 + threadIdx.x; i < n; i += 2048) {
      int o = i / K, k = i - o * K;
      d[k * O + o] = s[i];
    }
  } else if (bid < 152) {
    int q = bid - 24, m = q >> 4, sub = q & 15;
    const float* src = p.ssrc[m];
    unsigned short* dst = wsu + p.sOff[m];
    int K = p.sK[m], Ks = p.sKs[m], stride = p.sSt[m], n = p.sO[m] * K, S = K >> 5;
    for (int f = sub * 256 + threadIdx.x; f < n; f += 16 * 256) {
      int j = f & 7, l = (f >> 3) & 63, rest = f >> 9;
      int s = rest % S, c = rest / S;
      int row = c * 16 + (l & 15), col = s * 32 + ((l >> 4) << 3) + j;
      dst[f] = (col < Ks) ? f2bf(src[row * stride + col]) : (unsigned short)0;
    }
  } else {
    int i = (bid - 152) * 256 + threadIdx.x;  // 2048
    int j = i >> 8, o = i & 255;
    ws[TMB + i] = p.tm_b1[o] + p.tm_w1[o * 72 + 64 + j];
  }
}

// fused fc1 + GRU + teammate MLP + CE (all MFMA): 64 rows/block, 4 waves, 16 rows/wave
// smem partition (shorts): in[64*168) @0 ; x[64*72) @10752 ; hid[64*264) overlays @0 ; h[64*72) @16896
__global__ __launch_bounds__(256) void k_agent(
    const float* __restrict__ inp, const float* __restrict__ hin,
    const unsigned short* __restrict__ fc1bf, const unsigned short* __restrict__ wihbf,
    const unsigned short* __restrict__ whhbf, const unsigned short* __restrict__ tm1bf,
    const unsigned short* __restrict__ tm2bf,
    const float* __restrict__ fc1_b, const float* __restrict__ bih, const float* __restrict__ bhh,
    const float* __restrict__ tmB, const float* __restrict__ tm_b2, const int* __restrict__ u,
    float* __restrict__ hout, float* __restrict__ act, float* __restrict__ l1p)
{
  __shared__ __align__(16) unsigned short smem[21504];
  __shared__ float red[256];
  unsigned short* in_b  = smem;           // stride 168
  unsigned short* x_b   = smem + 10752;   // stride 72
  unsigned short* hid_b = smem;           // stride 264 (phase C overlay)
  unsigned short* h_b   = smem + 16896;   // stride 72
  int tid = threadIdx.x, w = tid >> 6, lane = tid & 63;
  int lo = lane & 15, hi = lane >> 4;
  int row0 = blockIdx.x * 64, wr0 = w * 16;

  // ---- stage (wave-local rows) ----
  for (int idx = lane; idx < 16 * 168; idx += 64) {
    int r = idx / 168, c = idx - r * 168;
    unsigned short v = 0;
    if (c < 152) v = f2bf(inp[(size_t)(row0 + wr0 + r) * 152 + c]);
    if (c < 160) in_b[(wr0 + r) * 168 + c] = v;
  }
  for (int idx = lane; idx < 16 * 64; idx += 64) {
    int r = idx >> 6, c = idx & 63;
    h_b[(wr0 + r) * 72 + c] = f2bf(hin[(size_t)(row0 + wr0 + r) * 64 + c]);
  }

  // ---- phase A: fc1 (K=160 padded) ----
  f32x4 acc1[4];
#pragma unroll
  for (int c = 0; c < 4; c++) acc1[c] = {0, 0, 0, 0};
#pragma unroll
  for (int s = 0; s < 5; s++) {
    bf16x8 af = *(const bf16x8*)(in_b + (wr0 + lo) * 168 + s * 32 + hi * 8);
#pragma unroll
    for (int c = 0; c < 4; c++) {
      bf16x8 bf = *(const bf16x8*)(fc1bf + (size_t)((c * 5 + s) * 64 + lane) * 8);
      acc1[c] = MFMA16(af, bf, acc1[c]);
    }
  }
#pragma unroll
  for (int c = 0; c < 4; c++)
#pragma unroll
    for (int r = 0; r < 4; r++) {
      int col = c * 16 + lo;
      x_b[(wr0 + hi * 4 + r) * 72 + col] = f2bf(fmaxf(acc1[c][r] + fc1_b[col], 0.f));
    }

  // ---- phase B: GRU gi/gh GEMMs ----
  f32x4 ai[12], ah[12];
#pragma unroll
  for (int c = 0; c < 12; c++) { ai[c] = {0, 0, 0, 0}; ah[c] = {0, 0, 0, 0}; }
#pragma unroll
  for (int s = 0; s < 2; s++) {
    bf16x8 ax = *(const bf16x8*)(x_b + (wr0 + lo) * 72 + s * 32 + hi * 8);
    bf16x8 ahf = *(const bf16x8*)(h_b + (wr0 + lo) * 72 + s * 32 + hi * 8);
#pragma unroll
    for (int c = 0; c < 12; c++) {
      bf16x8 bi = *(const bf16x8*)(wihbf + (size_t)((c * 2 + s) * 64 + lane) * 8);
      bf16x8 bh = *(const bf16x8*)(whhbf + (size_t)((c * 2 + s) * 64 + lane) * 8);
      ai[c] = MFMA16(ax, bi, ai[c]);
      ah[c] = MFMA16(ahf, bh, ah[c]);
    }
  }
  // ---- gates ----
#pragma unroll
  for (int q = 0; q < 4; q++) {
    int col = q * 16 + lo;
    float b_ir = bih[col], b_hr = bhh[col];
    float b_iz = bih[64 + col], b_hz = bhh[64 + col];
    float b_in = bih[128 + col], b_hn = bhh[128 + col];
#pragma unroll
    for (int r = 0; r < 4; r++) {
      int rl = hi * 4 + r;
      size_t grow = (size_t)(row0 + wr0 + rl);
      float irv = ai[q][r] + b_ir, hrv = ah[q][r] + b_hr;
      float izv = ai[q + 4][r] + b_iz, hzv = ah[q + 4][r] + b_hz;
      float inv_ = ai[q + 8][r] + b_in, hnv = ah[q + 8][r] + b_hn;
      float rg = 1.f / (1.f + expf(-(irv + hrv)));
      float zg = 1.f / (1.f + expf(-(izv + hzv)));
      float ng = tanhf(fmaf(rg, hnv, inv_));
      float h0 = hin[grow * 64 + col];
      float hv = (1.f - zg) * ng + zg * h0;
      hout[grow * 64 + col] = hv;
      h_b[(wr0 + rl) * 72 + col] = f2bf(hv);
    }
  }
  __syncthreads();   // hid overlay aliases other waves' in/x regions

  // ---- phase C: teammate MLP ----
  f32x4 at[16];
#pragma unroll
  for (int c = 0; c < 16; c++) at[c] = {0, 0, 0, 0};
#pragma unroll
  for (int s = 0; s < 2; s++) {
    bf16x8 af = *(const bf16x8*)(h_b + (wr0 + lo) * 72 + s * 32 + hi * 8);
#pragma unroll
    for (int c = 0; c < 16; c++) {
      bf16x8 bf = *(const bf16x8*)(tm1bf + (size_t)((c * 2 + s) * 64 + lane) * 8);
      at[c] = MFMA16(af, bf, at[c]);
    }
  }
#pragma unroll
  for (int c = 0; c < 16; c++)
#pragma unroll
    for (int r = 0; r < 4; r++) {
      int rl = hi * 4 + r, j = rl & 7, col = c * 16 + lo;
      hid_b[(wr0 + rl) * 264 + col] = f2bf(fmaxf(at[c][r] + tmB[j * 256 + col], 0.f));
    }
  f32x4 a2 = {0, 0, 0, 0};
#pragma unroll
  for (int s = 0; s < 8; s++) {
    bf16x8 af = *(const bf16x8*)(hid_b + (wr0 + lo) * 264 + s * 32 + hi * 8);
    bf16x8 bf = *(const bf16x8*)(tm2bf + (size_t)(s * 64 + lane) * 8);
    a2 = MFMA16(af, bf, a2);
  }
  float b2c = tm_b2[lo];
  float ces = 0.f;
#pragma unroll
  for (int r = 0; r < 4; r++) {
    int rl = hi * 4 + r;
    size_t grow = (size_t)(row0 + wr0 + rl);
    float v = a2[r] + b2c;
    act[grow * 16 + lo] = v;
    float m = v;
    m = fmaxf(m, __shfl_xor(m, 1));
    m = fmaxf(m, __shfl_xor(m, 2));
    m = fmaxf(m, __shfl_xor(m, 4));
    m = fmaxf(m, __shfl_xor(m, 8));
    float se = expf(v - m);
    se += __shfl_xor(se, 1);
    se += __shfl_xor(se, 2);
    se += __shfl_xor(se, 4);
    se += __shfl_xor(se, 8);
    int lbl = u[grow];
    float vl = __shfl(v, (lane & 48) + lbl);
    if (lo == 0) ces += -(vl - m - logf(se));
  }
  red[tid] = ces;
  __syncthreads();
  for (int st = 128; st > 0; st >>= 1) {
    if (tid < st) red[tid] += red[tid + st];
    __syncthreads();
  }
  if (tid == 0) l1p[blockIdx.x] = red[0];
}

// world model + MSE + query (MFMA, weight-stationary): 64 rows/block, 8 waves
__global__ __launch_bounds__(512) void k_wm(
    const float* __restrict__ obs, const float* __restrict__ act,
    const unsigned short* __restrict__ w1b, const unsigned short* __restrict__ w2b,
    const unsigned short* __restrict__ wqb,
    const float* __restrict__ b1, const float* __restrict__ b2, const float* __restrict__ bq,
    const float* __restrict__ obsn,
    float* __restrict__ qry, float* __restrict__ l2p)
{
  __shared__ __align__(16) unsigned short in_s[64 * 264];   // [obs | masked act] -> hid overlay
  __shared__ __align__(16) unsigned short q_in[64 * 264];   // [obs | onh]
  __shared__ __align__(16) unsigned short act_bs[8 * 128];
  __shared__ float red[512];
  int tid = threadIdx.x, w = tid >> 6, lane = tid & 63;
  int lo = lane & 15, hi = lane >> 4;
  int row0 = blockIdx.x * 64, e0 = row0 >> 3;
  for (int i = tid; i < 1024; i += 512) act_bs[i] = f2bf(act[(size_t)e0 * 128 + i]);
  for (int i = tid; i < 8192; i += 512) {
    int r = i >> 7, c = i & 127;
    unsigned short v = f2bf(obs[(size_t)(row0 + r) * 128 + c]);
    in_s[r * 264 + c] = v;
    q_in[r * 264 + c] = v;
  }
  bf16x8 wf1[2][8], wf2[8];
#pragma unroll
  for (int cc = 0; cc < 2; cc++)
#pragma unroll
    for (int s = 0; s < 8; s++)
      wf1[cc][s] = *(const bf16x8*)(w1b + (size_t)(((2 * w + cc) * 8 + s) * 64 + lane) * 8);
#pragma unroll
  for (int s = 0; s < 8; s++)
    wf2[s] = *(const bf16x8*)(w2b + (size_t)((w * 8 + s) * 64 + lane) * 8);
  __syncthreads();
  for (int i = tid; i < 8192; i += 512) {
    int r = i >> 7, c = i & 127;
    in_s[r * 264 + 128 + c] = ((c >> 4) == (r & 7)) ? (unsigned short)0 : act_bs[(r >> 3) * 128 + c];
  }
  __syncthreads();
  // layer1
  f32x4 acc[4][2];
#pragma unroll
  for (int rt = 0; rt < 4; rt++) { acc[rt][0] = {0,0,0,0}; acc[rt][1] = {0,0,0,0}; }
#pragma unroll
  for (int s = 0; s < 8; s++)
#pragma unroll
    for (int rt = 0; rt < 4; rt++) {
      bf16x8 af = *(const bf16x8*)(in_s + (rt * 16 + lo) * 264 + s * 32 + hi * 8);
      acc[rt][0] = MFMA16(af, wf1[0][s], acc[rt][0]);
      acc[rt][1] = MFMA16(af, wf1[1][s], acc[rt][1]);
    }
  float b1a = b1[32 * w + lo], b1b = b1[32 * w + 16 + lo];
  __syncthreads();
#pragma unroll
  for (int rt = 0; rt < 4; rt++)
#pragma unroll
    for (int r = 0; r < 4; r++) {
      int rowl = rt * 16 + hi * 4 + r;
      in_s[rowl * 264 + 32 * w + lo]      = f2bf(fmaxf(acc[rt][0][r] + b1a, 0.f));
      in_s[rowl * 264 + 32 * w + 16 + lo] = f2bf(fmaxf(acc[rt][1][r] + b1b, 0.f));
    }
  __syncthreads();
  // layer2 -> onh (LDS only) + MSE
  f32x4 acc2[4];
#pragma unroll
  for (int rt = 0; rt < 4; rt++) acc2[rt] = {0, 0, 0, 0};
#pragma unroll
  for (int s = 0; s < 8; s++)
#pragma unroll
    for (int rt = 0; rt < 4; rt++) {
      bf16x8 af = *(const bf16x8*)(in_s + (rt * 16 + lo) * 264 + s * 32 + hi * 8);
      acc2[rt] = MFMA16(af, wf2[s], acc2[rt]);
    }
  int col = 16 * w + lo;
  float b2c = b2[col];
  float ms = 0.f;
#pragma unroll
  for (int rt = 0; rt < 4; rt++)
#pragma unroll
    for (int r = 0; r < 4; r++) {
      int rowl = rt * 16 + hi * 4 + r;
      float v = acc2[rt][r] + b2c;
      q_in[rowl * 264 + 128 + col] = f2bf(v);
      float d = v - obsn[(size_t)(row0 + rowl) * 128 + col];
      ms = fmaf(d, d, ms);
    }
  __syncthreads();
  // query: c = w&3, row-half = w>>2
  int c = w & 3, rth = w >> 2;
  bf16x8 wf3[8];
#pragma unroll
  for (int s = 0; s < 8; s++)
    wf3[s] = *(const bf16x8*)(wqb + (size_t)((c * 8 + s) * 64 + lane) * 8);
  f32x4 aq[2];
  aq[0] = {0, 0, 0, 0}; aq[1] = {0, 0, 0, 0};
#pragma unroll
  for (int s = 0; s < 8; s++)
#pragma unroll
    for (int rl = 0; rl < 2; rl++) {
      bf16x8 af = *(const bf16x8*)(q_in + ((rth * 2 + rl) * 16 + lo) * 264 + s * 32 + hi * 8);
      aq[rl] = MFMA16(af, wf3[s], aq[rl]);
    }
  float bqc = bq[16 * c + lo];
#pragma unroll
  for (int rl = 0; rl < 2; rl++)
#pragma unroll
    for (int r = 0; r < 4; r++) {
      int row = row0 + (rth * 2 + rl) * 16 + hi * 4 + r;
      qry[(size_t)row * 64 + 16 * c + lo] = aq[rl][r] + bqc;
    }
  red[tid] = ms;
  __syncthreads();
  for (int st = 256; st > 0; st >>= 1) {
    if (tid < st) red[tid] += red[tid + st];
    __syncthreads();
  }
  if (tid == 0) l2p[blockIdx.x] = red[0];
}

// fused key + value + attention: 32 rows/block (4 episodes), wave = episode
__global__ __launch_bounds__(256) void k_kva(
    const float* __restrict__ h, const float* __restrict__ act,
    const float* __restrict__ ws, const float* __restrict__ bk,
    const float* __restrict__ bv1, const float* __restrict__ bv2,
    const float* __restrict__ qry, float* __restrict__ qout)
{
  __shared__ __align__(16) float in_s[32 * 80];
  __shared__ __align__(16) float hid_s[32 * 64];
  __shared__ __align__(16) float key_s[32 * 68];
  __shared__ float val_s[32 * 16];
  __shared__ float qs[4][64];
  int tid = threadIdx.x, w = tid >> 6, lane = tid & 63;
  int row0 = blockIdx.x * 32;
  for (int i = tid; i < 2048; i += 256) {
    int r = i >> 6, c = i & 63;
    in_s[r * 80 + c] = h[(size_t)row0 * 64 + i];
  }
  for (int i = tid; i < 512; i += 256) {
    int r = i >> 4, c = i & 15;
    in_s[r * 80 + 64 + c] = act[(size_t)row0 * 16 + i];
  }
  __syncthreads();
  const float* w1T = ws + T_WV1;
  const float* w2T = ws + T_WV2;
  const float* wkT = ws + T_WK;
  float acc[8];
#pragma unroll
  for (int r = 0; r < 8; r++) acc[r] = bv1[lane];
  for (int k = 0; k < 80; k += 4) {
    float b[4];
#pragma unroll
    for (int j = 0; j < 4; j++) b[j] = w1T[(k + j) * 64 + lane];
#pragma unroll
    for (int r = 0; r < 8; r++) {
      float4 a = LD4(in_s + (w * 8 + r) * 80 + k);
      acc[r] = fmaf(a.x, b[0], fmaf(a.y, b[1], fmaf(a.z, b[2], fmaf(a.w, b[3], acc[r]))));
    }
  }
#pragma unroll
  for (int r = 0; r < 8; r++) hid_s[(w * 8 + r) * 64 + lane] = fmaxf(acc[r], 0.f);
  float ka[8];
#pragma unroll
  for (int r = 0; r < 8; r++) ka[r] = bk[lane];
  for (int k = 0; k < 16; k += 4) {
    float b[4];
#pragma unroll
    for (int j = 0; j < 4; j++) b[j] = wkT[(k + j) * 64 + lane];
#pragma unroll
    for (int r = 0; r < 8; r++) {
      float4 a = LD4(in_s + (w * 8 + r) * 80 + 64 + k);
      ka[r] = fmaf(a.x, b[0], fmaf(a.y, b[1], fmaf(a.z, b[2], fmaf(a.w, b[3], ka[r]))));
    }
  }
#pragma unroll
  for (int r = 0; r < 8; r++) key_s[(w * 8 + r) * 68 + lane] = ka[r];
  int col = lane & 15, kq = lane >> 4;
  float a2[8] = {0, 0, 0, 0, 0, 0, 0, 0};
  for (int kk = 0; kk < 16; kk += 4) {
    int k = kq * 16 + kk;
    float b[4];
#pragma unroll
    for (int j = 0; j < 4; j++) b[j] = w2T[(k + j) * 16 + col];
#pragma unroll
    for (int r = 0; r < 8; r++) {
      float4 a = LD4(hid_s + (w * 8 + r) * 64 + k);
      a2[r] = fmaf(a.x, b[0], fmaf(a.y, b[1], fmaf(a.z, b[2], fmaf(a.w, b[3], a2[r]))));
    }
  }
#pragma unroll
  for (int r = 0; r < 8; r++) {
    a2[r] += __shfl_xor(a2[r], 16);
    a2[r] += __shfl_xor(a2[r], 32);
  }
  if (lane < 16) {
#pragma unroll
    for (int r = 0; r < 8; r++) val_s[(w * 8 + r) * 16 + col] = a2[r] + bv2[col];
  }
  int j = lane >> 3, p = lane & 7;
  for (int rr = 0; rr < 8; rr++) {
    int b = row0 + w * 8 + rr;
    qs[w][lane] = qry[(size_t)b * 64 + lane];
    const float* krow = key_s + (w * 8 + j) * 68;
    float s = 0.f;
#pragma unroll
    for (int t = 0; t < 8; t++) {
      int d = p * 8 + t;
      s = fmaf(qs[w][d], krow[d], s);
    }
    s += __shfl_xor(s, 1);
    s += __shfl_xor(s, 2);
    s += __shfl_xor(s, 4);
    float score = (j == rr) ? -1e9f : s * 0.125f;
    float sc[8];
    float m = -1e30f;
#pragma unroll
    for (int jj = 0; jj < 8; jj++) {
      sc[jj] = __shfl(score, jj * 8);
      m = fmaxf(m, sc[jj]);
    }
    float ssum = 0.f;
#pragma unroll
    for (int jj = 0; jj < 8; jj++) { sc[jj] = expf(sc[jj] - m); ssum += sc[jj]; }
    float inv = 1.f / ssum;
    int c = lane & 15, g = lane >> 4;
    const float* vb = val_s + w * 8 * 16;
    float outv = sc[g] * inv * vb[g * 16 + c] + sc[g + 4] * inv * vb[(g + 4) * 16 + c];
    outv += __shfl_xor(outv, 16);
    outv += __shfl_xor(outv, 32);
    if (lane < 16) qout[(size_t)b * 16 + lane] = outv;
  }
}

__global__ __launch_bounds__(256) void k_losses(
    const float* __restrict__ l1p, const float* __restrict__ l2p, float* __restrict__ dout)
{
  __shared__ float red[256];
  int tid = threadIdx.x;
  red[tid] = l1p[tid];
  __syncthreads();
  for (int s = 128; s > 0; s >>= 1) {
    if (tid < s) red[tid] += red[tid + s];
    __syncthreads();
  }
  float S1 = red[0];
  __syncthreads();
  red[tid] = l2p[tid];
  __syncthreads();
  for (int s = 128; s > 0; s >>= 1) {
    if (tid < s) red[tid] += red[tid + s];
    __syncthreads();
  }
  if (tid == 0) {
    dout[DO_L1] = S1 * 7.f / 131072.f;
    dout[DO_L2] = red[0] / 2097152.f;
  }
}

extern "C" void kernel_launch(void* const* d_in, const int* in_sizes, int n_in,
                              void* d_out, int out_size, void* d_ws, size_t ws_size,
                              hipStream_t stream) {
  const float* inputs   = (const float*)d_in[0];
  const float* hidden   = (const float*)d_in[1];
  const float* obs      = (const float*)d_in[2];
  const float* obs_next = (const float*)d_in[3];
  const int*   u        = (const int*)d_in[4];
  const float* fc1_w = (const float*)d_in[5];   const float* fc1_b = (const float*)d_in[6];
  const float* wih   = (const float*)d_in[7];   const float* bih   = (const float*)d_in[8];
  const float* whh   = (const float*)d_in[9];   const float* bhh   = (const float*)d_in[10];
  const float* tm_w1 = (const float*)d_in[11];  const float* tm_b1 = (const float*)d_in[12];
  const float* tm_w2 = (const float*)d_in[13];  const float* tm_b2 = (const float*)d_in[14];
  const float* wm_w1 = (const float*)d_in[15];  const float* wm_b1 = (const float*)d_in[16];
  const float* wm_w2 = (const float*)d_in[17];  const float* wm_b2 = (const float*)d_in[18];
  const float* wq_w  = (const float*)d_in[19];  const float* wq_b  = (const float*)d_in[20];
  const float* wk_w  = (const float*)d_in[21];  const float* wk_b  = (const float*)d_in[22];
  const float* wv1_w = (const float*)d_in[23];  const float* wv1_b = (const float*)d_in[24];
  const float* wv2_w = (const float*)d_in[25];  const float* wv2_b = (const float*)d_in[26];

  float* ws   = (float*)d_ws;
  unsigned short* wsu = (unsigned short*)d_ws;
  float* out  = (float*)d_out;
  float* hbuf = out + DO_H;

  PrepP p;
  const float* tsr[3] = {wk_w, wv1_w, wv2_w};
  int tO[3]  = {64, 64, 16};
  int tK[3]  = {16, 80, 64};
  int tOf[3] = {T_WK, T_WV1, T_WV2};
  for (int i = 0; i < 3; i++) { p.tsrc[i] = tsr[i]; p.tO[i] = tO[i]; p.tK[i] = tK[i]; p.tOff[i] = tOf[i]; }
  const float* ssr[8] = {wm_w1, wm_w2, wq_w, tm_w1, tm_w2, fc1_w, wih, whh};
  int sO[8]  = {256, 128, 64, 256, 16, 64, 192, 192};
  int sK[8]  = {256, 256, 256, 64, 256, 160, 64, 64};
  int sKs[8] = {256, 256, 256, 64, 256, 152, 64, 64};
  int sSt[8] = {256, 256, 256, 72, 256, 152, 64, 64};
  int sOf[8] = {B_WM1*2, B_WM2*2, B_WQ*2, B_TM1*2, B_TM2*2, B_FC1*2, B_WIH*2, B_WHH*2};
  for (int i = 0; i < 8; i++) {
    p.ssrc[i] = ssr[i]; p.sO[i] = sO[i]; p.sK[i] = sK[i];
    p.sKs[i] = sKs[i]; p.sSt[i] = sSt[i]; p.sOff[i] = sOf[i];
  }
  p.tm_w1 = tm_w1; p.tm_b1 = tm_b1;

  k_prep<<<160, 256, 0, stream>>>(p, ws, wsu);
  k_agent<<<ROWS / 64, 256, 0, stream>>>(inputs, hidden,
      wsu + B_FC1*2, wsu + B_WIH*2, wsu + B_WHH*2, wsu + B_TM1*2, wsu + B_TM2*2,
      fc1_b, bih, bhh, ws + TMB, tm_b2, u, hbuf, ws + O_ACT, ws + O_L1P);
  k_wm<<<ROWS / 64, 512, 0, stream>>>(obs, ws + O_ACT,
      wsu + B_WM1*2, wsu + B_WM2*2, wsu + B_WQ*2, wm_b1, wm_b2, wq_b, obs_next,
      ws + O_QRY, ws + O_L2P);
  k_kva<<<ROWS / 32, 256, 0, stream>>>(hbuf, ws + O_ACT, ws, wk_b, wv1_b, wv2_b, ws + O_QRY, out);
  k_losses<<<1, 256, 0, stream>>>(ws + O_L1P, ws + O_L2P, out);
}

// Round 6
// 62.980 us; speedup vs baseline: 1.6132x; 1.6132x over previous
//
#include <hip/hip_runtime.h>
#include <math.h>

#define E_NUM 2048
#define A_N   8
#define ROWS  (E_NUM*A_N)   // 16384

typedef __attribute__((ext_vector_type(8))) short bf16x8;
typedef __attribute__((ext_vector_type(4))) float f32x4;

__device__ __forceinline__ unsigned short f2bf(float x) {
  unsigned int u = __float_as_uint(x);
  return (unsigned short)((u + 0x7FFFu + ((u >> 16) & 1u)) >> 16);
}
#define MFMA16(a,b,c) __builtin_amdgcn_mfma_f32_16x16x32_bf16(a,b,c,0,0,0)

// ---- ws layout (float offsets) ----
#define T_WK   0         // 16*64 f32 transposed
#define T_WV1  1024      // 80*64
#define T_WV2  6144      // 64*16
#define TMB    7168      // 8*256 f32: tm_b1[o] + tm_w1[o][64+j]
#define B_WM1  9216      // 256x256 bf16 frag-major (32768 fl)
#define B_WM2  41984     // 128x256 (16384 fl)
#define B_WQ   58368     // 64x256 (8192 fl)
#define B_TM1  66560     // 256x64 (8192 fl)
#define B_TM2  74752     // 16x256 (2048 fl)
#define B_FC1  76800     // 64x160 (5120 fl)
#define B_WIH  81920     // 192x64 (6144 fl)
#define B_WHH  88064     // 192x64 (6144 fl)
#define O_ACT  94208     // 16384*16 f32
#define O_QRY  356352    // 16384*64 f32
#define O_L1P  1404928   // 256
#define O_L2P  1405184   // 256

// d_out: q_reflect [0,262144) ; h ; loss1 ; loss2
#define DO_H   262144
#define DO_L1  1310720
#define DO_L2  1310721

#define LD4(p) (*(const float4*)(p))

struct PrepP {
  const float* tsrc[3]; int tO[3], tK[3], tOff[3];
  const float* ssrc[8]; int sO[8], sK[8], sKs[8], sSt[8], sOff[8]; // sOff in ushort units
  const float* tm_w1; const float* tm_b1;
};

// blocks 0..23: f32 transpose ; 24..151: bf16 frag swizzle (w/ K zero-pad) ; 152..159: tmB
__global__ __launch_bounds__(256) void k_prep(PrepP p, float* __restrict__ ws,
                                              unsigned short* __restrict__ wsu) {
  int bid = blockIdx.x;
  if (bid < 24) {
    int b = bid >> 3, sl = bid & 7;
    const float* s = p.tsrc[b];
    float* d = ws + p.tOff[b];
    int O = p.tO[b], K = p.tK[b], n = O * K;
    for (int i = sl * 256 + threadIdx.x; i < n; i += 2048) {
      int o = i / K, k = i - o * K;
      d[k * O + o] = s[i];
    }
  } else if (bid < 152) {
    int q = bid - 24, m = q >> 4, sub = q & 15;
    const float* src = p.ssrc[m];
    unsigned short* dst = wsu + p.sOff[m];
    int K = p.sK[m], Ks = p.sKs[m], stride = p.sSt[m], n = p.sO[m] * K, S = K >> 5;
    for (int f = sub * 256 + threadIdx.x; f < n; f += 16 * 256) {
      int j = f & 7, l = (f >> 3) & 63, rest = f >> 9;
      int s = rest % S, c = rest / S;
      int row = c * 16 + (l & 15), col = s * 32 + ((l >> 4) << 3) + j;
      dst[f] = (col < Ks) ? f2bf(src[row * stride + col]) : (unsigned short)0;
    }
  } else {
    int i = (bid - 152) * 256 + threadIdx.x;  // 2048
    int j = i >> 8, o = i & 255;
    ws[TMB + i] = p.tm_b1[o] + p.tm_w1[o * 72 + 64 + j];
  }
}

// fc1 + GRU (MFMA, weight-stationary): 64 rows/block, 8 waves (512 thr)
// wave w: rth = w>>2 (row half: 2 row-tiles), c = w&3 (col chunk of 16)
__global__ __launch_bounds__(512) void k_trunk(
    const float* __restrict__ inp, const float* __restrict__ hin,
    const unsigned short* __restrict__ fc1bf, const unsigned short* __restrict__ wihbf,
    const unsigned short* __restrict__ whhbf,
    const float* __restrict__ fc1_b, const float* __restrict__ bih, const float* __restrict__ bhh,
    float* __restrict__ hout)
{
  __shared__ __align__(16) unsigned short in_b[64 * 168];
  __shared__ __align__(16) unsigned short x_b[64 * 72];
  __shared__ __align__(16) unsigned short h_b[64 * 72];
  int tid = threadIdx.x, w = tid >> 6, lane = tid & 63;
  int lo = lane & 15, hi = lane >> 4;
  int row0 = blockIdx.x * 64;
  int c = w & 3, rth = w >> 2;

  for (int i = tid; i < 64 * 152; i += 512) {
    int r = i / 152, cc = i - r * 152;
    in_b[r * 168 + cc] = f2bf(inp[(size_t)(row0 + r) * 152 + cc]);
  }
  { int r = tid >> 3, cc = tid & 7; in_b[r * 168 + 152 + cc] = 0; }
  for (int i = tid; i < 64 * 64; i += 512) {
    int r = i >> 6, cc = i & 63;
    h_b[r * 72 + cc] = f2bf(hin[(size_t)(row0 + r) * 64 + cc]);
  }
  __syncthreads();

  // fc1: K=160 (5 s-steps), wave cols 16c..16c+15, rows rth*32..+31
  bf16x8 wf1[5];
#pragma unroll
  for (int s = 0; s < 5; s++)
    wf1[s] = *(const bf16x8*)(fc1bf + (size_t)((c * 5 + s) * 64 + lane) * 8);
  f32x4 acc[2];
  acc[0] = {0, 0, 0, 0}; acc[1] = {0, 0, 0, 0};
#pragma unroll
  for (int s = 0; s < 5; s++)
#pragma unroll
    for (int rt = 0; rt < 2; rt++) {
      int R = rth * 2 + rt;
      bf16x8 af = *(const bf16x8*)(in_b + (R * 16 + lo) * 168 + s * 32 + hi * 8);
      acc[rt] = MFMA16(af, wf1[s], acc[rt]);
    }
  float fb = fc1_b[16 * c + lo];
#pragma unroll
  for (int rt = 0; rt < 2; rt++)
#pragma unroll
    for (int r = 0; r < 4; r++) {
      int R = rth * 2 + rt;
      x_b[(R * 16 + hi * 4 + r) * 72 + 16 * c + lo] = f2bf(fmaxf(acc[rt][r] + fb, 0.f));
    }
  __syncthreads();

  // GRU: wave computes gi/gh chunks {c, c+4, c+8} (= r/z/n gate cols 16c+lo)
  bf16x8 wfi[3][2], wfh[3][2];
#pragma unroll
  for (int t = 0; t < 3; t++)
#pragma unroll
    for (int s = 0; s < 2; s++) {
      int chunk = c + 4 * t;
      wfi[t][s] = *(const bf16x8*)(wihbf + (size_t)((chunk * 2 + s) * 64 + lane) * 8);
      wfh[t][s] = *(const bf16x8*)(whhbf + (size_t)((chunk * 2 + s) * 64 + lane) * 8);
    }
  f32x4 ai[2][3], ah[2][3];
#pragma unroll
  for (int rt = 0; rt < 2; rt++)
#pragma unroll
    for (int t = 0; t < 3; t++) { ai[rt][t] = {0,0,0,0}; ah[rt][t] = {0,0,0,0}; }
#pragma unroll
  for (int s = 0; s < 2; s++)
#pragma unroll
    for (int rt = 0; rt < 2; rt++) {
      int R = rth * 2 + rt;
      bf16x8 ax  = *(const bf16x8*)(x_b + (R * 16 + lo) * 72 + s * 32 + hi * 8);
      bf16x8 ahv = *(const bf16x8*)(h_b + (R * 16 + lo) * 72 + s * 32 + hi * 8);
#pragma unroll
      for (int t = 0; t < 3; t++) {
        ai[rt][t] = MFMA16(ax,  wfi[t][s], ai[rt][t]);
        ah[rt][t] = MFMA16(ahv, wfh[t][s], ah[rt][t]);
      }
    }
  int col = 16 * c + lo;
  float b_ir = bih[col],       b_hr = bhh[col];
  float b_iz = bih[64 + col],  b_hz = bhh[64 + col];
  float b_in = bih[128 + col], b_hn = bhh[128 + col];
#pragma unroll
  for (int rt = 0; rt < 2; rt++)
#pragma unroll
    for (int r = 0; r < 4; r++) {
      int R = rth * 2 + rt;
      size_t grow = (size_t)(row0 + R * 16 + hi * 4 + r);
      float rg = 1.f / (1.f + expf(-(ai[rt][0][r] + b_ir + ah[rt][0][r] + b_hr)));
      float zg = 1.f / (1.f + expf(-(ai[rt][1][r] + b_iz + ah[rt][1][r] + b_hz)));
      float ng = tanhf(fmaf(rg, ah[rt][2][r] + b_hn, ai[rt][2][r] + b_in));
      float h0 = hin[grow * 64 + col];
      hout[grow * 64 + col] = (1.f - zg) * ng + zg * h0;
    }
}

// teammate MLP + CE (MFMA, weight-stationary): 64 rows/block, 8 waves
__global__ __launch_bounds__(512) void k_tm(
    const float* __restrict__ h,
    const unsigned short* __restrict__ w1b, const unsigned short* __restrict__ w2b,
    const float* __restrict__ tmB, const float* __restrict__ b2,
    const int* __restrict__ u,
    float* __restrict__ act, float* __restrict__ l1p)
{
  __shared__ __align__(16) unsigned short in_s[64 * 72];
  __shared__ __align__(16) unsigned short hid_s[64 * 264];
  __shared__ float red[512];
  int tid = threadIdx.x, w = tid >> 6, lane = tid & 63;
  int lo = lane & 15, hi = lane >> 4;
  int row0 = blockIdx.x * 64;
  for (int i = tid; i < 4096; i += 512) {
    int r = i >> 6, c = i & 63;
    in_s[r * 72 + c] = f2bf(h[(size_t)(row0 + r) * 64 + c]);
  }
  bf16x8 wf1[2][2];
#pragma unroll
  for (int cc = 0; cc < 2; cc++)
#pragma unroll
    for (int s = 0; s < 2; s++)
      wf1[cc][s] = *(const bf16x8*)(w1b + (size_t)(((2 * w + cc) * 2 + s) * 64 + lane) * 8);
  __syncthreads();
  f32x4 acc[4][2];
#pragma unroll
  for (int rt = 0; rt < 4; rt++) { acc[rt][0] = {0,0,0,0}; acc[rt][1] = {0,0,0,0}; }
#pragma unroll
  for (int s = 0; s < 2; s++)
#pragma unroll
    for (int rt = 0; rt < 4; rt++) {
      bf16x8 af = *(const bf16x8*)(in_s + (rt * 16 + lo) * 72 + s * 32 + hi * 8);
      acc[rt][0] = MFMA16(af, wf1[0][s], acc[rt][0]);
      acc[rt][1] = MFMA16(af, wf1[1][s], acc[rt][1]);
    }
#pragma unroll
  for (int rt = 0; rt < 4; rt++)
#pragma unroll
    for (int r = 0; r < 4; r++) {
      int rowl = rt * 16 + hi * 4 + r, j = (hi * 4 + r) & 7;
      float v0 = acc[rt][0][r] + tmB[j * 256 + 32 * w + lo];
      float v1 = acc[rt][1][r] + tmB[j * 256 + 32 * w + 16 + lo];
      hid_s[rowl * 264 + 32 * w + lo]      = f2bf(fmaxf(v0, 0.f));
      hid_s[rowl * 264 + 32 * w + 16 + lo] = f2bf(fmaxf(v1, 0.f));
    }
  __syncthreads();
  float ces = 0.f;
  if (w < 4) {
    bf16x8 wf2[8];
#pragma unroll
    for (int s = 0; s < 8; s++)
      wf2[s] = *(const bf16x8*)(w2b + (size_t)(s * 64 + lane) * 8);
    f32x4 a2 = {0, 0, 0, 0};
#pragma unroll
    for (int s = 0; s < 8; s++) {
      bf16x8 af = *(const bf16x8*)(hid_s + (w * 16 + lo) * 264 + s * 32 + hi * 8);
      a2 = MFMA16(af, wf2[s], a2);
    }
    float b2c = b2[lo];
#pragma unroll
    for (int r = 0; r < 4; r++) {
      int rowl = w * 16 + hi * 4 + r;
      float v = a2[r] + b2c;
      act[(size_t)(row0 + rowl) * 16 + lo] = v;
      float m = v;
      m = fmaxf(m, __shfl_xor(m, 1));
      m = fmaxf(m, __shfl_xor(m, 2));
      m = fmaxf(m, __shfl_xor(m, 4));
      m = fmaxf(m, __shfl_xor(m, 8));
      float se = expf(v - m);
      se += __shfl_xor(se, 1);
      se += __shfl_xor(se, 2);
      se += __shfl_xor(se, 4);
      se += __shfl_xor(se, 8);
      int lbl = u[row0 + rowl];
      float vl = __shfl(v, (lane & 48) + lbl);
      float ce = -(vl - m - logf(se));
      if (lo == 0) ces += ce;
    }
  }
  red[tid] = ces;
  __syncthreads();
  for (int st = 256; st > 0; st >>= 1) {
    if (tid < st) red[tid] += red[tid + st];
    __syncthreads();
  }
  if (tid == 0) l1p[blockIdx.x] = red[0];
}

// world model + MSE + query (MFMA, weight-stationary): 64 rows/block, 8 waves
__global__ __launch_bounds__(512) void k_wm(
    const float* __restrict__ obs, const float* __restrict__ act,
    const unsigned short* __restrict__ w1b, const unsigned short* __restrict__ w2b,
    const unsigned short* __restrict__ wqb,
    const float* __restrict__ b1, const float* __restrict__ b2, const float* __restrict__ bq,
    const float* __restrict__ obsn,
    float* __restrict__ qry, float* __restrict__ l2p)
{
  __shared__ __align__(16) unsigned short in_s[64 * 264];   // [obs | masked act] -> hid overlay
  __shared__ __align__(16) unsigned short q_in[64 * 264];   // [obs | onh]
  __shared__ __align__(16) unsigned short act_bs[8 * 128];
  __shared__ float red[512];
  int tid = threadIdx.x, w = tid >> 6, lane = tid & 63;
  int lo = lane & 15, hi = lane >> 4;
  int row0 = blockIdx.x * 64, e0 = row0 >> 3;
  for (int i = tid; i < 1024; i += 512) act_bs[i] = f2bf(act[(size_t)e0 * 128 + i]);
  for (int i = tid; i < 8192; i += 512) {
    int r = i >> 7, c = i & 127;
    unsigned short v = f2bf(obs[(size_t)(row0 + r) * 128 + c]);
    in_s[r * 264 + c] = v;
    q_in[r * 264 + c] = v;
  }
  bf16x8 wf1[2][8], wf2[8];
#pragma unroll
  for (int cc = 0; cc < 2; cc++)
#pragma unroll
    for (int s = 0; s < 8; s++)
      wf1[cc][s] = *(const bf16x8*)(w1b + (size_t)(((2 * w + cc) * 8 + s) * 64 + lane) * 8);
#pragma unroll
  for (int s = 0; s < 8; s++)
    wf2[s] = *(const bf16x8*)(w2b + (size_t)((w * 8 + s) * 64 + lane) * 8);
  __syncthreads();
  for (int i = tid; i < 8192; i += 512) {
    int r = i >> 7, c = i & 127;
    in_s[r * 264 + 128 + c] = ((c >> 4) == (r & 7)) ? (unsigned short)0 : act_bs[(r >> 3) * 128 + c];
  }
  __syncthreads();
  f32x4 acc[4][2];
#pragma unroll
  for (int rt = 0; rt < 4; rt++) { acc[rt][0] = {0,0,0,0}; acc[rt][1] = {0,0,0,0}; }
#pragma unroll
  for (int s = 0; s < 8; s++)
#pragma unroll
    for (int rt = 0; rt < 4; rt++) {
      bf16x8 af = *(const bf16x8*)(in_s + (rt * 16 + lo) * 264 + s * 32 + hi * 8);
      acc[rt][0] = MFMA16(af, wf1[0][s], acc[rt][0]);
      acc[rt][1] = MFMA16(af, wf1[1][s], acc[rt][1]);
    }
  float b1a = b1[32 * w + lo], b1b = b1[32 * w + 16 + lo];
  __syncthreads();
#pragma unroll
  for (int rt = 0; rt < 4; rt++)
#pragma unroll
    for (int r = 0; r < 4; r++) {
      int rowl = rt * 16 + hi * 4 + r;
      in_s[rowl * 264 + 32 * w + lo]      = f2bf(fmaxf(acc[rt][0][r] + b1a, 0.f));
      in_s[rowl * 264 + 32 * w + 16 + lo] = f2bf(fmaxf(acc[rt][1][r] + b1b, 0.f));
    }
  __syncthreads();
  f32x4 acc2[4];
#pragma unroll
  for (int rt = 0; rt < 4; rt++) acc2[rt] = {0, 0, 0, 0};
#pragma unroll
  for (int s = 0; s < 8; s++)
#pragma unroll
    for (int rt = 0; rt < 4; rt++) {
      bf16x8 af = *(const bf16x8*)(in_s + (rt * 16 + lo) * 264 + s * 32 + hi * 8);
      acc2[rt] = MFMA16(af, wf2[s], acc2[rt]);
    }
  int col = 16 * w + lo;
  float b2c = b2[col];
  float ms = 0.f;
#pragma unroll
  for (int rt = 0; rt < 4; rt++)
#pragma unroll
    for (int r = 0; r < 4; r++) {
      int rowl = rt * 16 + hi * 4 + r;
      float v = acc2[rt][r] + b2c;
      q_in[rowl * 264 + 128 + col] = f2bf(v);
      float d = v - obsn[(size_t)(row0 + rowl) * 128 + col];
      ms = fmaf(d, d, ms);
    }
  __syncthreads();
  int c = w & 3, rth = w >> 2;
  bf16x8 wf3[8];
#pragma unroll
  for (int s = 0; s < 8; s++)
    wf3[s] = *(const bf16x8*)(wqb + (size_t)((c * 8 + s) * 64 + lane) * 8);
  f32x4 aq[2];
  aq[0] = {0, 0, 0, 0}; aq[1] = {0, 0, 0, 0};
#pragma unroll
  for (int s = 0; s < 8; s++)
#pragma unroll
    for (int rl = 0; rl < 2; rl++) {
      bf16x8 af = *(const bf16x8*)(q_in + ((rth * 2 + rl) * 16 + lo) * 264 + s * 32 + hi * 8);
      aq[rl] = MFMA16(af, wf3[s], aq[rl]);
    }
  float bqc = bq[16 * c + lo];
#pragma unroll
  for (int rl = 0; rl < 2; rl++)
#pragma unroll
    for (int r = 0; r < 4; r++) {
      int row = row0 + (rth * 2 + rl) * 16 + hi * 4 + r;
      qry[(size_t)row * 64 + 16 * c + lo] = aq[rl][r] + bqc;
    }
  red[tid] = ms;
  __syncthreads();
  for (int st = 256; st > 0; st >>= 1) {
    if (tid < st) red[tid] += red[tid + st];
    __syncthreads();
  }
  if (tid == 0) l2p[blockIdx.x] = red[0];
}

// fused key + value + attention: 32 rows/block (4 episodes), wave = episode
__global__ __launch_bounds__(256) void k_kva(
    const float* __restrict__ h, const float* __restrict__ act,
    const float* __restrict__ ws, const float* __restrict__ bk,
    const float* __restrict__ bv1, const float* __restrict__ bv2,
    const float* __restrict__ qry, float* __restrict__ qout)
{
  __shared__ __align__(16) float in_s[32 * 80];
  __shared__ __align__(16) float hid_s[32 * 64];
  __shared__ __align__(16) float key_s[32 * 68];
  __shared__ float val_s[32 * 16];
  __shared__ float qs[4][64];
  int tid = threadIdx.x, w = tid >> 6, lane = tid & 63;
  int row0 = blockIdx.x * 32;
  for (int i = tid; i < 2048; i += 256) {
    int r = i >> 6, c = i & 63;
    in_s[r * 80 + c] = h[(size_t)row0 * 64 + i];
  }
  for (int i = tid; i < 512; i += 256) {
    int r = i >> 4, c = i & 15;
    in_s[r * 80 + 64 + c] = act[(size_t)row0 * 16 + i];
  }
  __syncthreads();
  const float* w1T = ws + T_WV1;
  const float* w2T = ws + T_WV2;
  const float* wkT = ws + T_WK;
  float acc[8];
#pragma unroll
  for (int r = 0; r < 8; r++) acc[r] = bv1[lane];
  for (int k = 0; k < 80; k += 4) {
    float b[4];
#pragma unroll
    for (int j = 0; j < 4; j++) b[j] = w1T[(k + j) * 64 + lane];
#pragma unroll
    for (int r = 0; r < 8; r++) {
      float4 a = LD4(in_s + (w * 8 + r) * 80 + k);
      acc[r] = fmaf(a.x, b[0], fmaf(a.y, b[1], fmaf(a.z, b[2], fmaf(a.w, b[3], acc[r]))));
    }
  }
#pragma unroll
  for (int r = 0; r < 8; r++) hid_s[(w * 8 + r) * 64 + lane] = fmaxf(acc[r], 0.f);
  float ka[8];
#pragma unroll
  for (int r = 0; r < 8; r++) ka[r] = bk[lane];
  for (int k = 0; k < 16; k += 4) {
    float b[4];
#pragma unroll
    for (int j = 0; j < 4; j++) b[j] = wkT[(k + j) * 64 + lane];
#pragma unroll
    for (int r = 0; r < 8; r++) {
      float4 a = LD4(in_s + (w * 8 + r) * 80 + 64 + k);
      ka[r] = fmaf(a.x, b[0], fmaf(a.y, b[1], fmaf(a.z, b[2], fmaf(a.w, b[3], ka[r]))));
    }
  }
#pragma unroll
  for (int r = 0; r < 8; r++) key_s[(w * 8 + r) * 68 + lane] = ka[r];
  int col = lane & 15, kq = lane >> 4;
  float a2[8] = {0, 0, 0, 0, 0, 0, 0, 0};
  for (int kk = 0; kk < 16; kk += 4) {
    int k = kq * 16 + kk;
    float b[4];
#pragma unroll
    for (int j = 0; j < 4; j++) b[j] = w2T[(k + j) * 16 + col];
#pragma unroll
    for (int r = 0; r < 8; r++) {
      float4 a = LD4(hid_s + (w * 8 + r) * 64 + k);
      a2[r] = fmaf(a.x, b[0], fmaf(a.y, b[1], fmaf(a.z, b[2], fmaf(a.w, b[3], a2[r]))));
    }
  }
#pragma unroll
  for (int r = 0; r < 8; r++) {
    a2[r] += __shfl_xor(a2[r], 16);
    a2[r] += __shfl_xor(a2[r], 32);
  }
  if (lane < 16) {
#pragma unroll
    for (int r = 0; r < 8; r++) val_s[(w * 8 + r) * 16 + col] = a2[r] + bv2[col];
  }
  int j = lane >> 3, p = lane & 7;
  for (int rr = 0; rr < 8; rr++) {
    int b = row0 + w * 8 + rr;
    qs[w][lane] = qry[(size_t)b * 64 + lane];
    const float* krow = key_s + (w * 8 + j) * 68;
    float s = 0.f;
#pragma unroll
    for (int t = 0; t < 8; t++) {
      int d = p * 8 + t;
      s = fmaf(qs[w][d], krow[d], s);
    }
    s += __shfl_xor(s, 1);
    s += __shfl_xor(s, 2);
    s += __shfl_xor(s, 4);
    float score = (j == rr) ? -1e9f : s * 0.125f;
    float sc[8];
    float m = -1e30f;
#pragma unroll
    for (int jj = 0; jj < 8; jj++) {
      sc[jj] = __shfl(score, jj * 8);
      m = fmaxf(m, sc[jj]);
    }
    float ssum = 0.f;
#pragma unroll
    for (int jj = 0; jj < 8; jj++) { sc[jj] = expf(sc[jj] - m); ssum += sc[jj]; }
    float inv = 1.f / ssum;
    int c = lane & 15, g = lane >> 4;
    const float* vb = val_s + w * 8 * 16;
    float outv = sc[g] * inv * vb[g * 16 + c] + sc[g + 4] * inv * vb[(g + 4) * 16 + c];
    outv += __shfl_xor(outv, 16);
    outv += __shfl_xor(outv, 32);
    if (lane < 16) qout[(size_t)b * 16 + lane] = outv;
  }
}

__global__ __launch_bounds__(256) void k_losses(
    const float* __restrict__ l1p, const float* __restrict__ l2p, float* __restrict__ dout)
{
  __shared__ float red[256];
  int tid = threadIdx.x;
  red[tid] = l1p[tid];
  __syncthreads();
  for (int s = 128; s > 0; s >>= 1) {
    if (tid < s) red[tid] += red[tid + s];
    __syncthreads();
  }
  float S1 = red[0];
  __syncthreads();
  red[tid] = l2p[tid];
  __syncthreads();
  for (int s = 128; s > 0; s >>= 1) {
    if (tid < s) red[tid] += red[tid + s];
    __syncthreads();
  }
  if (tid == 0) {
    dout[DO_L1] = S1 * 7.f / 131072.f;
    dout[DO_L2] = red[0] / 2097152.f;
  }
}

extern "C" void kernel_launch(void* const* d_in, const int* in_sizes, int n_in,
                              void* d_out, int out_size, void* d_ws, size_t ws_size,
                              hipStream_t stream) {
  const float* inputs   = (const float*)d_in[0];
  const float* hidden   = (const float*)d_in[1];
  const float* obs      = (const float*)d_in[2];
  const float* obs_next = (const float*)d_in[3];
  const int*   u        = (const int*)d_in[4];
  const float* fc1_w = (const float*)d_in[5];   const float* fc1_b = (const float*)d_in[6];
  const float* wih   = (const float*)d_in[7];   const float* bih   = (const float*)d_in[8];
  const float* whh   = (const float*)d_in[9];   const float* bhh   = (const float*)d_in[10];
  const float* tm_w1 = (const float*)d_in[11];  const float* tm_b1 = (const float*)d_in[12];
  const float* tm_w2 = (const float*)d_in[13];  const float* tm_b2 = (const float*)d_in[14];
  const float* wm_w1 = (const float*)d_in[15];  const float* wm_b1 = (const float*)d_in[16];
  const float* wm_w2 = (const float*)d_in[17];  const float* wm_b2 = (const float*)d_in[18];
  const float* wq_w  = (const float*)d_in[19];  const float* wq_b  = (const float*)d_in[20];
  const float* wk_w  = (const float*)d_in[21];  const float* wk_b  = (const float*)d_in[22];
  const float* wv1_w = (const float*)d_in[23];  const float* wv1_b = (const float*)d_in[24];
  const float* wv2_w = (const float*)d_in[25];  const float* wv2_b = (const float*)d_in[26];

  float* ws   = (float*)d_ws;
  unsigned short* wsu = (unsigned short*)d_ws;
  float* out  = (float*)d_out;
  float* hbuf = out + DO_H;

  PrepP p;
  const float* tsr[3] = {wk_w, wv1_w, wv2_w};
  int tO[3]  = {64, 64, 16};
  int tK[3]  = {16, 80, 64};
  int tOf[3] = {T_WK, T_WV1, T_WV2};
  for (int i = 0; i < 3; i++) { p.tsrc[i] = tsr[i]; p.tO[i] = tO[i]; p.tK[i] = tK[i]; p.tOff[i] = tOf[i]; }
  const float* ssr[8] = {wm_w1, wm_w2, wq_w, tm_w1, tm_w2, fc1_w, wih, whh};
  int sO[8]  = {256, 128, 64, 256, 16, 64, 192, 192};
  int sK[8]  = {256, 256, 256, 64, 256, 160, 64, 64};
  int sKs[8] = {256, 256, 256, 64, 256, 152, 64, 64};
  int sSt[8] = {256, 256, 256, 72, 256, 152, 64, 64};
  int sOf[8] = {B_WM1*2, B_WM2*2, B_WQ*2, B_TM1*2, B_TM2*2, B_FC1*2, B_WIH*2, B_WHH*2};
  for (int i = 0; i < 8; i++) {
    p.ssrc[i] = ssr[i]; p.sO[i] = sO[i]; p.sK[i] = sK[i];
    p.sKs[i] = sKs[i]; p.sSt[i] = sSt[i]; p.sOff[i] = sOf[i];
  }
  p.tm_w1 = tm_w1; p.tm_b1 = tm_b1;

  k_prep<<<160, 256, 0, stream>>>(p, ws, wsu);
  k_trunk<<<ROWS / 64, 512, 0, stream>>>(inputs, hidden,
      wsu + B_FC1*2, wsu + B_WIH*2, wsu + B_WHH*2, fc1_b, bih, bhh, hbuf);
  k_tm<<<ROWS / 64, 512, 0, stream>>>(hbuf, wsu + B_TM1*2, wsu + B_TM2*2,
      ws + TMB, tm_b2, u, ws + O_ACT, ws + O_L1P);
  k_wm<<<ROWS / 64, 512, 0, stream>>>(obs, ws + O_ACT,
      wsu + B_WM1*2, wsu + B_WM2*2, wsu + B_WQ*2, wm_b1, wm_b2, wq_b, obs_next,
      ws + O_QRY, ws + O_L2P);
  k_kva<<<ROWS / 32, 256, 0, stream>>>(hbuf, ws + O_ACT, ws, wk_b, wv1_b, wv2_b, ws + O_QRY, out);
  k_losses<<<1, 256, 0, stream>>>(ws + O_L1P, ws + O_L2P, out);
}

// Round 7
// 58.696 us; speedup vs baseline: 1.7309x; 1.0730x over previous
//
#include <hip/hip_runtime.h>
#include <math.h>

#define E_NUM 2048
#define A_N   8
#define ROWS  (E_NUM*A_N)   // 16384

typedef __attribute__((ext_vector_type(8))) short bf16x8;
typedef __attribute__((ext_vector_type(4))) float f32x4;

__device__ __forceinline__ unsigned short f2bf(float x) {
  unsigned int u = __float_as_uint(x);
  return (unsigned short)((u + 0x7FFFu + ((u >> 16) & 1u)) >> 16);
}
#define MFMA16(a,b,c) __builtin_amdgcn_mfma_f32_16x16x32_bf16(a,b,c,0,0,0)

// ---- ws layout (float offsets) ----
#define T_WK   0         // 16*64 f32 transposed
#define T_WV1  1024      // 80*64
#define T_WV2  6144      // 64*16
#define TMB    7168      // 8*256 f32: tm_b1[o] + tm_w1[o][64+j]
#define B_WM1  9216      // 256x256 bf16 frag-major (32768 fl)
#define B_WM2  41984     // 128x256 (16384 fl)
#define B_WQ   58368     // 64x256 (8192 fl)
#define B_TM1  66560     // 256x64 (8192 fl)
#define B_TM2  74752     // 16x256 (2048 fl)
#define B_FC1  76800     // 64x160 (5120 fl)
#define B_WIH  81920     // 192x64 (6144 fl)
#define B_WHH  88064     // 192x64 (6144 fl)
#define O_ACT  94208     // 16384*16 f32
#define O_QRY  356352    // 16384*64 f32
#define O_L1P  1404928   // 512
#define O_L2P  1405440   // 512

// d_out: q_reflect [0,262144) ; h ; loss1 ; loss2
#define DO_H   262144
#define DO_L1  1310720
#define DO_L2  1310721

#define LD4(p) (*(const float4*)(p))

struct PrepP {
  const float* tsrc[3]; int tO[3], tK[3], tOff[3];
  const float* ssrc[8]; int sO[8], sK[8], sKs[8], sSt[8], sOff[8]; // sOff in ushort units
  const float* tm_w1; const float* tm_b1;
};

// blocks 0..23: f32 transpose ; 24..151: bf16 frag swizzle (w/ K zero-pad) ; 152..159: tmB
__global__ __launch_bounds__(256) void k_prep(PrepP p, float* __restrict__ ws,
                                              unsigned short* __restrict__ wsu) {
  int bid = blockIdx.x;
  if (bid < 24) {
    int b = bid >> 3, sl = bid & 7;
    const float* s = p.tsrc[b];
    float* d = ws + p.tOff[b];
    int O = p.tO[b], K = p.tK[b], n = O * K;
    for (int i = sl * 256 + threadIdx.x; i < n; i += 2048) {
      int o = i / K, k = i - o * K;
      d[k * O + o] = s[i];
    }
  } else if (bid < 152) {
    int q = bid - 24, m = q >> 4, sub = q & 15;
    const float* src = p.ssrc[m];
    unsigned short* dst = wsu + p.sOff[m];
    int K = p.sK[m], Ks = p.sKs[m], stride = p.sSt[m], n = p.sO[m] * K, S = K >> 5;
    for (int f = sub * 256 + threadIdx.x; f < n; f += 16 * 256) {
      int j = f & 7, l = (f >> 3) & 63, rest = f >> 9;
      int s = rest % S, c = rest / S;
      int row = c * 16 + (l & 15), col = s * 32 + ((l >> 4) << 3) + j;
      dst[f] = (col < Ks) ? f2bf(src[row * stride + col]) : (unsigned short)0;
    }
  } else {
    int i = (bid - 152) * 256 + threadIdx.x;  // 2048
    int j = i >> 8, o = i & 255;
    ws[TMB + i] = p.tm_b1[o] + p.tm_w1[o * 72 + 64 + j];
  }
}

// fc1 + GRU (MFMA, weight-stationary): 32 rows/block, 8 waves (512 thr)
// wave w: rt = w>>2 (row tile of 16), c = w&3 (col chunk of 16)
__global__ __launch_bounds__(512) void k_trunk(
    const float* __restrict__ inp, const float* __restrict__ hin,
    const unsigned short* __restrict__ fc1bf, const unsigned short* __restrict__ wihbf,
    const unsigned short* __restrict__ whhbf,
    const float* __restrict__ fc1_b, const float* __restrict__ bih, const float* __restrict__ bhh,
    float* __restrict__ hout)
{
  __shared__ __align__(16) unsigned short in_b[32 * 168];
  __shared__ __align__(16) unsigned short x_b[32 * 72];
  __shared__ __align__(16) unsigned short h_b[32 * 72];
  int tid = threadIdx.x, w = tid >> 6, lane = tid & 63;
  int lo = lane & 15, hi = lane >> 4;
  int row0 = blockIdx.x * 32;
  int c = w & 3, rt = w >> 2;

  for (int i = tid; i < 32 * 152; i += 512) {
    int r = i / 152, cc = i - r * 152;
    in_b[r * 168 + cc] = f2bf(inp[(size_t)(row0 + r) * 152 + cc]);
  }
  if (tid < 256) { int r = tid >> 3, cc = tid & 7; in_b[r * 168 + 152 + cc] = 0; }
  for (int i = tid; i < 32 * 64; i += 512) {
    int r = i >> 6, cc = i & 63;
    h_b[r * 72 + cc] = f2bf(hin[(size_t)(row0 + r) * 64 + cc]);
  }
  __syncthreads();

  // fc1: K=160 (5 s-steps), wave cols 16c..16c+15, rows rt*16..+15
  bf16x8 wf1[5];
#pragma unroll
  for (int s = 0; s < 5; s++)
    wf1[s] = *(const bf16x8*)(fc1bf + (size_t)((c * 5 + s) * 64 + lane) * 8);
  f32x4 acc = {0, 0, 0, 0};
#pragma unroll
  for (int s = 0; s < 5; s++) {
    bf16x8 af = *(const bf16x8*)(in_b + (rt * 16 + lo) * 168 + s * 32 + hi * 8);
    acc = MFMA16(af, wf1[s], acc);
  }
  float fb = fc1_b[16 * c + lo];
#pragma unroll
  for (int r = 0; r < 4; r++)
    x_b[(rt * 16 + hi * 4 + r) * 72 + 16 * c + lo] = f2bf(fmaxf(acc[r] + fb, 0.f));
  __syncthreads();

  // GRU: wave computes gi/gh chunks {c, c+4, c+8} (= r/z/n gate cols 16c+lo)
  bf16x8 wfi[3][2], wfh[3][2];
#pragma unroll
  for (int t = 0; t < 3; t++)
#pragma unroll
    for (int s = 0; s < 2; s++) {
      int chunk = c + 4 * t;
      wfi[t][s] = *(const bf16x8*)(wihbf + (size_t)((chunk * 2 + s) * 64 + lane) * 8);
      wfh[t][s] = *(const bf16x8*)(whhbf + (size_t)((chunk * 2 + s) * 64 + lane) * 8);
    }
  f32x4 ai[3], ah[3];
#pragma unroll
  for (int t = 0; t < 3; t++) { ai[t] = {0,0,0,0}; ah[t] = {0,0,0,0}; }
#pragma unroll
  for (int s = 0; s < 2; s++) {
    bf16x8 ax  = *(const bf16x8*)(x_b + (rt * 16 + lo) * 72 + s * 32 + hi * 8);
    bf16x8 ahv = *(const bf16x8*)(h_b + (rt * 16 + lo) * 72 + s * 32 + hi * 8);
#pragma unroll
    for (int t = 0; t < 3; t++) {
      ai[t] = MFMA16(ax,  wfi[t][s], ai[t]);
      ah[t] = MFMA16(ahv, wfh[t][s], ah[t]);
    }
  }
  int col = 16 * c + lo;
  float b_ir = bih[col],       b_hr = bhh[col];
  float b_iz = bih[64 + col],  b_hz = bhh[64 + col];
  float b_in = bih[128 + col], b_hn = bhh[128 + col];
#pragma unroll
  for (int r = 0; r < 4; r++) {
    size_t grow = (size_t)(row0 + rt * 16 + hi * 4 + r);
    float rg = 1.f / (1.f + expf(-(ai[0][r] + b_ir + ah[0][r] + b_hr)));
    float zg = 1.f / (1.f + expf(-(ai[1][r] + b_iz + ah[1][r] + b_hz)));
    float ng = tanhf(fmaf(rg, ah[2][r] + b_hn, ai[2][r] + b_in));
    float h0 = hin[grow * 64 + col];
    hout[grow * 64 + col] = (1.f - zg) * ng + zg * h0;
  }
}

// teammate MLP + CE (MFMA, weight-stationary): 32 rows/block, 8 waves
__global__ __launch_bounds__(512) void k_tm(
    const float* __restrict__ h,
    const unsigned short* __restrict__ w1b, const unsigned short* __restrict__ w2b,
    const float* __restrict__ tmB, const float* __restrict__ b2,
    const int* __restrict__ u,
    float* __restrict__ act, float* __restrict__ l1p)
{
  __shared__ __align__(16) unsigned short in_s[32 * 72];
  __shared__ __align__(16) unsigned short hid_s[32 * 264];
  __shared__ float red[512];
  int tid = threadIdx.x, w = tid >> 6, lane = tid & 63;
  int lo = lane & 15, hi = lane >> 4;
  int row0 = blockIdx.x * 32;
  for (int i = tid; i < 2048; i += 512) {
    int r = i >> 6, c = i & 63;
    in_s[r * 72 + c] = f2bf(h[(size_t)(row0 + r) * 64 + c]);
  }
  bf16x8 wf1[2][2];
#pragma unroll
  for (int cc = 0; cc < 2; cc++)
#pragma unroll
    for (int s = 0; s < 2; s++)
      wf1[cc][s] = *(const bf16x8*)(w1b + (size_t)(((2 * w + cc) * 2 + s) * 64 + lane) * 8);
  __syncthreads();
  f32x4 acc[2][2];
#pragma unroll
  for (int rt = 0; rt < 2; rt++) { acc[rt][0] = {0,0,0,0}; acc[rt][1] = {0,0,0,0}; }
#pragma unroll
  for (int s = 0; s < 2; s++)
#pragma unroll
    for (int rt = 0; rt < 2; rt++) {
      bf16x8 af = *(const bf16x8*)(in_s + (rt * 16 + lo) * 72 + s * 32 + hi * 8);
      acc[rt][0] = MFMA16(af, wf1[0][s], acc[rt][0]);
      acc[rt][1] = MFMA16(af, wf1[1][s], acc[rt][1]);
    }
#pragma unroll
  for (int rt = 0; rt < 2; rt++)
#pragma unroll
    for (int r = 0; r < 4; r++) {
      int rowl = rt * 16 + hi * 4 + r, j = (hi * 4 + r) & 7;
      float v0 = acc[rt][0][r] + tmB[j * 256 + 32 * w + lo];
      float v1 = acc[rt][1][r] + tmB[j * 256 + 32 * w + 16 + lo];
      hid_s[rowl * 264 + 32 * w + lo]      = f2bf(fmaxf(v0, 0.f));
      hid_s[rowl * 264 + 32 * w + 16 + lo] = f2bf(fmaxf(v1, 0.f));
    }
  __syncthreads();
  float ces = 0.f;
  if (w < 2) {
    bf16x8 wf2[8];
#pragma unroll
    for (int s = 0; s < 8; s++)
      wf2[s] = *(const bf16x8*)(w2b + (size_t)(s * 64 + lane) * 8);
    f32x4 a2 = {0, 0, 0, 0};
#pragma unroll
    for (int s = 0; s < 8; s++) {
      bf16x8 af = *(const bf16x8*)(hid_s + (w * 16 + lo) * 264 + s * 32 + hi * 8);
      a2 = MFMA16(af, wf2[s], a2);
    }
    float b2c = b2[lo];
#pragma unroll
    for (int r = 0; r < 4; r++) {
      int rowl = w * 16 + hi * 4 + r;
      float v = a2[r] + b2c;
      act[(size_t)(row0 + rowl) * 16 + lo] = v;
      float m = v;
      m = fmaxf(m, __shfl_xor(m, 1));
      m = fmaxf(m, __shfl_xor(m, 2));
      m = fmaxf(m, __shfl_xor(m, 4));
      m = fmaxf(m, __shfl_xor(m, 8));
      float se = expf(v - m);
      se += __shfl_xor(se, 1);
      se += __shfl_xor(se, 2);
      se += __shfl_xor(se, 4);
      se += __shfl_xor(se, 8);
      int lbl = u[row0 + rowl];
      float vl = __shfl(v, (lane & 48) + lbl);
      float ce = -(vl - m - logf(se));
      if (lo == 0) ces += ce;
    }
  }
  red[tid] = ces;
  __syncthreads();
  for (int st = 256; st > 0; st >>= 1) {
    if (tid < st) red[tid] += red[tid + st];
    __syncthreads();
  }
  if (tid == 0) l1p[blockIdx.x] = red[0];
}

// world model + MSE + query (MFMA, weight-stationary): 32 rows/block, 8 waves
__global__ __launch_bounds__(512) void k_wm(
    const float* __restrict__ obs, const float* __restrict__ act,
    const unsigned short* __restrict__ w1b, const unsigned short* __restrict__ w2b,
    const unsigned short* __restrict__ wqb,
    const float* __restrict__ b1, const float* __restrict__ b2, const float* __restrict__ bq,
    const float* __restrict__ obsn,
    float* __restrict__ qry, float* __restrict__ l2p)
{
  __shared__ __align__(16) unsigned short in_s[32 * 264];   // [obs | masked act] -> hid overlay
  __shared__ __align__(16) unsigned short q_in[32 * 264];   // [obs | onh]
  __shared__ __align__(16) unsigned short act_bs[4 * 128];
  __shared__ float red[512];
  int tid = threadIdx.x, w = tid >> 6, lane = tid & 63;
  int lo = lane & 15, hi = lane >> 4;
  int row0 = blockIdx.x * 32, e0 = row0 >> 3;
  if (tid < 512) {
    int i = tid;
    if (i < 512) act_bs[i & 511] = f2bf(act[(size_t)e0 * 128 + (i & 511)]);
  }
  for (int i = tid; i < 4096; i += 512) {
    int r = i >> 7, c = i & 127;
    unsigned short v = f2bf(obs[(size_t)(row0 + r) * 128 + c]);
    in_s[r * 264 + c] = v;
    q_in[r * 264 + c] = v;
  }
  bf16x8 wf1[2][8], wf2[8];
#pragma unroll
  for (int cc = 0; cc < 2; cc++)
#pragma unroll
    for (int s = 0; s < 8; s++)
      wf1[cc][s] = *(const bf16x8*)(w1b + (size_t)(((2 * w + cc) * 8 + s) * 64 + lane) * 8);
#pragma unroll
  for (int s = 0; s < 8; s++)
    wf2[s] = *(const bf16x8*)(w2b + (size_t)((w * 8 + s) * 64 + lane) * 8);
  __syncthreads();
  for (int i = tid; i < 4096; i += 512) {
    int r = i >> 7, c = i & 127;
    in_s[r * 264 + 128 + c] = ((c >> 4) == (r & 7)) ? (unsigned short)0 : act_bs[(r >> 3) * 128 + c];
  }
  __syncthreads();
  // layer1: wave w -> cols [32w, 32w+32)
  f32x4 acc[2][2];
#pragma unroll
  for (int rt = 0; rt < 2; rt++) { acc[rt][0] = {0,0,0,0}; acc[rt][1] = {0,0,0,0}; }
#pragma unroll
  for (int s = 0; s < 8; s++)
#pragma unroll
    for (int rt = 0; rt < 2; rt++) {
      bf16x8 af = *(const bf16x8*)(in_s + (rt * 16 + lo) * 264 + s * 32 + hi * 8);
      acc[rt][0] = MFMA16(af, wf1[0][s], acc[rt][0]);
      acc[rt][1] = MFMA16(af, wf1[1][s], acc[rt][1]);
    }
  float b1a = b1[32 * w + lo], b1b = b1[32 * w + 16 + lo];
  __syncthreads();
#pragma unroll
  for (int rt = 0; rt < 2; rt++)
#pragma unroll
    for (int r = 0; r < 4; r++) {
      int rowl = rt * 16 + hi * 4 + r;
      in_s[rowl * 264 + 32 * w + lo]      = f2bf(fmaxf(acc[rt][0][r] + b1a, 0.f));
      in_s[rowl * 264 + 32 * w + 16 + lo] = f2bf(fmaxf(acc[rt][1][r] + b1b, 0.f));
    }
  __syncthreads();
  // layer2: wave w -> cols [16w, 16w+16)
  f32x4 acc2[2];
  acc2[0] = {0, 0, 0, 0}; acc2[1] = {0, 0, 0, 0};
#pragma unroll
  for (int s = 0; s < 8; s++)
#pragma unroll
    for (int rt = 0; rt < 2; rt++) {
      bf16x8 af = *(const bf16x8*)(in_s + (rt * 16 + lo) * 264 + s * 32 + hi * 8);
      acc2[rt] = MFMA16(af, wf2[s], acc2[rt]);
    }
  int col = 16 * w + lo;
  float b2c = b2[col];
  float ms = 0.f;
#pragma unroll
  for (int rt = 0; rt < 2; rt++)
#pragma unroll
    for (int r = 0; r < 4; r++) {
      int rowl = rt * 16 + hi * 4 + r;
      float v = acc2[rt][r] + b2c;
      q_in[rowl * 264 + 128 + col] = f2bf(v);
      float d = v - obsn[(size_t)(row0 + rowl) * 128 + col];
      ms = fmaf(d, d, ms);
    }
  __syncthreads();
  // query: c = w&3 (16 cols), rt = w>>2
  int c = w & 3, rt = w >> 2;
  bf16x8 wf3[8];
#pragma unroll
  for (int s = 0; s < 8; s++)
    wf3[s] = *(const bf16x8*)(wqb + (size_t)((c * 8 + s) * 64 + lane) * 8);
  f32x4 aq = {0, 0, 0, 0};
#pragma unroll
  for (int s = 0; s < 8; s++) {
    bf16x8 af = *(const bf16x8*)(q_in + (rt * 16 + lo) * 264 + s * 32 + hi * 8);
    aq = MFMA16(af, wf3[s], aq);
  }
  float bqc = bq[16 * c + lo];
#pragma unroll
  for (int r = 0; r < 4; r++) {
    int row = row0 + rt * 16 + hi * 4 + r;
    qry[(size_t)row * 64 + 16 * c + lo] = aq[r] + bqc;
  }
  red[tid] = ms;
  __syncthreads();
  for (int st = 256; st > 0; st >>= 1) {
    if (tid < st) red[tid] += red[tid + st];
    __syncthreads();
  }
  if (tid == 0) l2p[blockIdx.x] = red[0];
}

// fused key + value + attention (+ block0: loss finalize): 32 rows/block, 4 waves
__global__ __launch_bounds__(256) void k_kva(
    const float* __restrict__ h, const float* __restrict__ act,
    const float* __restrict__ ws, const float* __restrict__ bk,
    const float* __restrict__ bv1, const float* __restrict__ bv2,
    const float* __restrict__ qry, const float* __restrict__ l1p,
    const float* __restrict__ l2p, float* __restrict__ qout)
{
  __shared__ __align__(16) float in_s[32 * 80];
  __shared__ __align__(16) float hid_s[32 * 64];
  __shared__ __align__(16) float key_s[32 * 68];
  __shared__ float val_s[32 * 16];
  __shared__ float qs[4][64];
  __shared__ float red2[256];
  int tid = threadIdx.x, w = tid >> 6, lane = tid & 63;
  int row0 = blockIdx.x * 32;
  if (blockIdx.x == 0) {
    // finalize losses (l1p/l2p fully written by prior kernels)
    float s1 = l1p[tid] + l1p[tid + 256];
    float s2 = l2p[tid] + l2p[tid + 256];
    red2[tid] = s1;
    __syncthreads();
    for (int s = 128; s > 0; s >>= 1) {
      if (tid < s) red2[tid] += red2[tid + s];
      __syncthreads();
    }
    float S1 = red2[0];
    __syncthreads();
    red2[tid] = s2;
    __syncthreads();
    for (int s = 128; s > 0; s >>= 1) {
      if (tid < s) red2[tid] += red2[tid + s];
      __syncthreads();
    }
    if (tid == 0) {
      qout[DO_L1] = S1 * 7.f / 131072.f;
      qout[DO_L2] = red2[0] / 2097152.f;
    }
    __syncthreads();
  }
  for (int i = tid; i < 2048; i += 256) {
    int r = i >> 6, c = i & 63;
    in_s[r * 80 + c] = h[(size_t)row0 * 64 + i];
  }
  for (int i = tid; i < 512; i += 256) {
    int r = i >> 4, c = i & 15;
    in_s[r * 80 + 64 + c] = act[(size_t)row0 * 16 + i];
  }
  __syncthreads();
  const float* w1T = ws + T_WV1;
  const float* w2T = ws + T_WV2;
  const float* wkT = ws + T_WK;
  float acc[8];
#pragma unroll
  for (int r = 0; r < 8; r++) acc[r] = bv1[lane];
  for (int k = 0; k < 80; k += 4) {
    float b[4];
#pragma unroll
    for (int j = 0; j < 4; j++) b[j] = w1T[(k + j) * 64 + lane];
#pragma unroll
    for (int r = 0; r < 8; r++) {
      float4 a = LD4(in_s + (w * 8 + r) * 80 + k);
      acc[r] = fmaf(a.x, b[0], fmaf(a.y, b[1], fmaf(a.z, b[2], fmaf(a.w, b[3], acc[r]))));
    }
  }
#pragma unroll
  for (int r = 0; r < 8; r++) hid_s[(w * 8 + r) * 64 + lane] = fmaxf(acc[r], 0.f);
  float ka[8];
#pragma unroll
  for (int r = 0; r < 8; r++) ka[r] = bk[lane];
  for (int k = 0; k < 16; k += 4) {
    float b[4];
#pragma unroll
    for (int j = 0; j < 4; j++) b[j] = wkT[(k + j) * 64 + lane];
#pragma unroll
    for (int r = 0; r < 8; r++) {
      float4 a = LD4(in_s + (w * 8 + r) * 80 + 64 + k);
      ka[r] = fmaf(a.x, b[0], fmaf(a.y, b[1], fmaf(a.z, b[2], fmaf(a.w, b[3], ka[r]))));
    }
  }
#pragma unroll
  for (int r = 0; r < 8; r++) key_s[(w * 8 + r) * 68 + lane] = ka[r];
  int col = lane & 15, kq = lane >> 4;
  float a2[8] = {0, 0, 0, 0, 0, 0, 0, 0};
  for (int kk = 0; kk < 16; kk += 4) {
    int k = kq * 16 + kk;
    float b[4];
#pragma unroll
    for (int j = 0; j < 4; j++) b[j] = w2T[(k + j) * 16 + col];
#pragma unroll
    for (int r = 0; r < 8; r++) {
      float4 a = LD4(hid_s + (w * 8 + r) * 64 + k);
      a2[r] = fmaf(a.x, b[0], fmaf(a.y, b[1], fmaf(a.z, b[2], fmaf(a.w, b[3], a2[r]))));
    }
  }
#pragma unroll
  for (int r = 0; r < 8; r++) {
    a2[r] += __shfl_xor(a2[r], 16);
    a2[r] += __shfl_xor(a2[r], 32);
  }
  if (lane < 16) {
#pragma unroll
    for (int r = 0; r < 8; r++) val_s[(w * 8 + r) * 16 + col] = a2[r] + bv2[col];
  }
  int j = lane >> 3, p = lane & 7;
  for (int rr = 0; rr < 8; rr++) {
    int b = row0 + w * 8 + rr;
    qs[w][lane] = qry[(size_t)b * 64 + lane];
    const float* krow = key_s + (w * 8 + j) * 68;
    float s = 0.f;
#pragma unroll
    for (int t = 0; t < 8; t++) {
      int d = p * 8 + t;
      s = fmaf(qs[w][d], krow[d], s);
    }
    s += __shfl_xor(s, 1);
    s += __shfl_xor(s, 2);
    s += __shfl_xor(s, 4);
    float score = (j == rr) ? -1e9f : s * 0.125f;
    float sc[8];
    float m = -1e30f;
#pragma unroll
    for (int jj = 0; jj < 8; jj++) {
      sc[jj] = __shfl(score, jj * 8);
      m = fmaxf(m, sc[jj]);
    }
    float ssum = 0.f;
#pragma unroll
    for (int jj = 0; jj < 8; jj++) { sc[jj] = expf(sc[jj] - m); ssum += sc[jj]; }
    float inv = 1.f / ssum;
    int c = lane & 15, g = lane >> 4;
    const float* vb = val_s + w * 8 * 16;
    float outv = sc[g] * inv * vb[g * 16 + c] + sc[g + 4] * inv * vb[(g + 4) * 16 + c];
    outv += __shfl_xor(outv, 16);
    outv += __shfl_xor(outv, 32);
    if (lane < 16) qout[(size_t)b * 16 + lane] = outv;
  }
}

extern "C" void kernel_launch(void* const* d_in, const int* in_sizes, int n_in,
                              void* d_out, int out_size, void* d_ws, size_t ws_size,
                              hipStream_t stream) {
  const float* inputs   = (const float*)d_in[0];
  const float* hidden   = (const float*)d_in[1];
  const float* obs      = (const float*)d_in[2];
  const float* obs_next = (const float*)d_in[3];
  const int*   u        = (const int*)d_in[4];
  const float* fc1_w = (const float*)d_in[5];   const float* fc1_b = (const float*)d_in[6];
  const float* wih   = (const float*)d_in[7];   const float* bih   = (const float*)d_in[8];
  const float* whh   = (const float*)d_in[9];   const float* bhh   = (const float*)d_in[10];
  const float* tm_w1 = (const float*)d_in[11];  const float* tm_b1 = (const float*)d_in[12];
  const float* tm_w2 = (const float*)d_in[13];  const float* tm_b2 = (const float*)d_in[14];
  const float* wm_w1 = (const float*)d_in[15];  const float* wm_b1 = (const float*)d_in[16];
  const float* wm_w2 = (const float*)d_in[17];  const float* wm_b2 = (const float*)d_in[18];
  const float* wq_w  = (const float*)d_in[19];  const float* wq_b  = (const float*)d_in[20];
  const float* wk_w  = (const float*)d_in[21];  const float* wk_b  = (const float*)d_in[22];
  const float* wv1_w = (const float*)d_in[23];  const float* wv1_b = (const float*)d_in[24];
  const float* wv2_w = (const float*)d_in[25];  const float* wv2_b = (const float*)d_in[26];

  float* ws   = (float*)d_ws;
  unsigned short* wsu = (unsigned short*)d_ws;
  float* out  = (float*)d_out;
  float* hbuf = out + DO_H;

  PrepP p;
  const float* tsr[3] = {wk_w, wv1_w, wv2_w};
  int tO[3]  = {64, 64, 16};
  int tK[3]  = {16, 80, 64};
  int tOf[3] = {T_WK, T_WV1, T_WV2};
  for (int i = 0; i < 3; i++) { p.tsrc[i] = tsr[i]; p.tO[i] = tO[i]; p.tK[i] = tK[i]; p.tOff[i] = tOf[i]; }
  const float* ssr[8] = {wm_w1, wm_w2, wq_w, tm_w1, tm_w2, fc1_w, wih, whh};
  int sO[8]  = {256, 128, 64, 256, 16, 64, 192, 192};
  int sK[8]  = {256, 256, 256, 64, 256, 160, 64, 64};
  int sKs[8] = {256, 256, 256, 64, 256, 152, 64, 64};
  int sSt[8] = {256, 256, 256, 72, 256, 152, 64, 64};
  int sOf[8] = {B_WM1*2, B_WM2*2, B_WQ*2, B_TM1*2, B_TM2*2, B_FC1*2, B_WIH*2, B_WHH*2};
  for (int i = 0; i < 8; i++) {
    p.ssrc[i] = ssr[i]; p.sO[i] = sO[i]; p.sK[i] = sK[i];
    p.sKs[i] = sKs[i]; p.sSt[i] = sSt[i]; p.sOff[i] = sOf[i];
  }
  p.tm_w1 = tm_w1; p.tm_b1 = tm_b1;

  k_prep<<<160, 256, 0, stream>>>(p, ws, wsu);
  k_trunk<<<ROWS / 32, 512, 0, stream>>>(inputs, hidden,
      wsu + B_FC1*2, wsu + B_WIH*2, wsu + B_WHH*2, fc1_b, bih, bhh, hbuf);
  k_tm<<<ROWS / 32, 512, 0, stream>>>(hbuf, wsu + B_TM1*2, wsu + B_TM2*2,
      ws + TMB, tm_b2, u, ws + O_ACT, ws + O_L1P);
  k_wm<<<ROWS / 32, 512, 0, stream>>>(obs, ws + O_ACT,
      wsu + B_WM1*2, wsu + B_WM2*2, wsu + B_WQ*2, wm_b1, wm_b2, wq_b, obs_next,
      ws + O_QRY, ws + O_L2P);
  k_kva<<<ROWS / 32, 256, 0, stream>>>(hbuf, ws + O_ACT, ws, wk_b, wv1_b, wv2_b,
      ws + O_QRY, ws + O_L1P, ws + O_L2P, out);
}